// Round 12
// baseline (265.945 us; speedup 1.0000x reference)
//
#include <hip/hip_runtime.h>

typedef unsigned short u16;
typedef __attribute__((ext_vector_type(8))) short s8b;       // 8 x bf16 bits
typedef __attribute__((ext_vector_type(4))) float f4;
typedef __attribute__((ext_vector_type(8))) _Float16 h8;     // 8 x f16

static __device__ __forceinline__ float b2f(u16 u){
  return __uint_as_float(((unsigned int)u) << 16);
}
static __device__ __forceinline__ u16 f2b(float f){
  unsigned int u = __float_as_uint(f);
  u = (u + 0x7FFFu + ((u >> 16) & 1u)) >> 16;   // RNE
  return (u16)u;
}
static __device__ __forceinline__ f4 mfma16(s8b a, s8b b, f4 c){
  return __builtin_amdgcn_mfma_f32_16x16x32_bf16(a, b, c, 0, 0, 0);
}
static __device__ __forceinline__ s8b load8(const float* p){
  float4 a = ((const float4*)p)[0];
  float4 b = ((const float4*)p)[1];
  s8b r;
  r[0] = (short)f2b(a.x); r[1] = (short)f2b(a.y);
  r[2] = (short)f2b(a.z); r[3] = (short)f2b(a.w);
  r[4] = (short)f2b(b.x); r[5] = (short)f2b(b.y);
  r[6] = (short)f2b(b.z); r[7] = (short)f2b(b.w);
  return r;
}
// async global->LDS, 16B per lane. Per-lane lds ptr must equal wave-uniform + lane*16.
static __device__ __forceinline__ void gload16(const u16* g, u16* l){
  __builtin_amdgcn_global_load_lds((const __attribute__((address_space(1))) void*)g,
                                   (__attribute__((address_space(3))) void*)l,
                                   16, 0, 0);
}

// ------------- fp32 -> bf16 bulk convert (8 elems/thread) ------------------
__global__ void convert_k(const float* __restrict__ in, u16* __restrict__ out,
                          int n8){
  const int i = blockIdx.x * blockDim.x + threadIdx.x;
  if (i < n8) ((s8b*)out)[i] = load8(in + (size_t)i * 8);
}

// ------------- transpose: in[K][N] fp32 -> out[N][K] bf16 ------------------
__global__ void transpose_k(const float* __restrict__ in, u16* __restrict__ out,
                            int K, int N){
  __shared__ u16 tile[32][33];
  const int n0 = blockIdx.x << 5, k0 = blockIdx.y << 5;
  const int tx = threadIdx.x, ty = threadIdx.y;   // block (32,8)
  #pragma unroll
  for (int i = ty; i < 32; i += 8)
    tile[i][tx] = f2b(in[(size_t)(k0 + i) * N + n0 + tx]);
  __syncthreads();
  #pragma unroll
  for (int i = ty; i < 32; i += 8)
    out[(size_t)(n0 + i) * K + k0 + tx] = tile[tx][i];
}

// ------------- fused Wq/Wk/Wv transpose into WT rows [0,2048|2048,2560|2560,3072)
__global__ void transpose3_k(const float* __restrict__ Wq,
                             const float* __restrict__ Wk,
                             const float* __restrict__ Wv,
                             u16* __restrict__ out){
  __shared__ u16 tile[32][33];
  int bx = blockIdx.x;
  const float* src; int N; int rowoff;
  if (bx < 64)      { src = Wq; N = 2048; rowoff = 0; }
  else if (bx < 80) { src = Wk; N = 512;  rowoff = 2048; bx -= 64; }
  else              { src = Wv; N = 512;  rowoff = 2560; bx -= 80; }
  const int n0 = bx << 5, k0 = blockIdx.y << 5;
  const int tx = threadIdx.x, ty = threadIdx.y;   // block (32,8)
  #pragma unroll
  for (int i = ty; i < 32; i += 8)
    tile[i][tx] = f2b(src[(size_t)(k0 + i) * N + n0 + tx]);
  __syncthreads();
  #pragma unroll
  for (int i = ty; i < 32; i += 8)
    out[(size_t)(rowoff + n0 + i) * 2048 + k0 + tx] = tile[tx][i];
}

// ------------- 4-wave MFMA GEMM, 128x128 tile, 64x64 wave-tile, BK=32 ------
// R12: LDS-read economy. Per-CU ds_read_b128 pipe time (4608 reads x ~10cy)
// dwarfs MFMA issue (~3us) -> gemm was LDS-read bound; schedule changes were
// neutral (R9-R11). Wave-tile 64x64 (acc[4][4]): 8 ds_read per 16 MFMA vs
// 6 per 8 -> 1.5x fewer reads/FLOP at the SAME 128^2 tile and grid.
// 256 threads = 4 waves (2x2). R8's proven 2-phase/2-barrier shape, vmcnt(4)
// (4 gloads/thread/stage). Zero-conflict XOR swizzle (R8-verified) unchanged.
// T1 XCD swizzle REVERTED (R11: FETCH +37%, hurt).
template <int MODE>
__global__ __launch_bounds__(256) void gemm8(const u16* __restrict__ A,
                                             const u16* __restrict__ Bt,
                                             u16* __restrict__ Cq,
                                             u16* __restrict__ Ck,
                                             u16* __restrict__ Cv,
                                             float* __restrict__ Cf,
                                             int M, int K){
  __shared__ __align__(16) u16 As[2][128 * 32];
  __shared__ __align__(16) u16 Bs[2][128 * 32];
  const int n0 = blockIdx.x << 7;
  const int m0 = blockIdx.y << 7;
  const int tid = threadIdx.x;
  const int wave = tid >> 6, lane = tid & 63;
  const int quad = lane >> 4, ln = lane & 15;
  const int wr = (wave >> 1) << 6;     // 0 / 64
  const int wc = (wave & 1) << 6;      // 0 / 64
  // staging: 512 slots per operand (128 rows x 4 granules), 2 slots/thread
  const int ar = tid >> 2, gr = tid & 3;
  const int gsw = (gr ^ ((ar >> 1) & 3)) << 3;    // pre-swizzled src granule
  const int rsw = ((ln >> 1) & 3) << 3;           // read-side XOR partner

  f4 acc[4][4];
  #pragma unroll
  for (int i = 0; i < 4; ++i)
    #pragma unroll
    for (int j = 0; j < 4; ++j){ f4 z = {0.f,0.f,0.f,0.f}; acc[i][j] = z; }

  const u16* agp0 = A  + (size_t)(m0 + ar) * K + gsw;
  const u16* agp1 = A  + (size_t)(m0 + ar + 64) * K + gsw;   // ((ar+64)>>1)&3 == (ar>>1)&3
  const u16* bgp0 = Bt + (size_t)(n0 + ar) * K + gsw;
  const u16* bgp1 = Bt + (size_t)(n0 + ar + 64) * K + gsw;
  const int NT = K >> 5;

  // prologue: stage tile 0 into buffer 0
  gload16(agp0, As[0] + tid * 8);
  gload16(agp1, As[0] + (tid + 256) * 8);
  gload16(bgp0, Bs[0] + tid * 8);
  gload16(bgp1, Bs[0] + (tid + 256) * 8);

  for (int t = 0; t < NT; ++t){
    const int cur = t & 1;
    const int kn = ((t + 1) < NT ? (t + 1) : t) << 5;
    gload16(agp0 + kn, As[cur ^ 1] + tid * 8);
    gload16(agp1 + kn, As[cur ^ 1] + (tid + 256) * 8);
    gload16(bgp0 + kn, Bs[cur ^ 1] + tid * 8);
    gload16(bgp1 + kn, Bs[cur ^ 1] + (tid + 256) * 8);
    asm volatile("s_waitcnt vmcnt(4)" ::: "memory");
    __builtin_amdgcn_s_barrier();
    s8b af[4], bf[4];
    #pragma unroll
    for (int i = 0; i < 4; ++i)
      af[i] = *(const s8b*)&As[cur][(wr + i*16 + ln)*32 + ((quad*8) ^ rsw)];
    #pragma unroll
    for (int j = 0; j < 4; ++j)
      bf[j] = *(const s8b*)&Bs[cur][(wc + j*16 + ln)*32 + ((quad*8) ^ rsw)];
    #pragma unroll
    for (int i = 0; i < 4; ++i)
      #pragma unroll
      for (int j = 0; j < 4; ++j)
        acc[i][j] = mfma16(af[i], bf[j], acc[i][j]);
    asm volatile("s_waitcnt lgkmcnt(0)" ::: "memory");
    __builtin_amdgcn_s_barrier();
  }
  // C/D layout: col = ln, row = quad*4 + r (m89/m91-verified)
  #pragma unroll
  for (int i = 0; i < 4; ++i)
    #pragma unroll
    for (int j = 0; j < 4; ++j)
      #pragma unroll
      for (int r = 0; r < 4; ++r){
        const int row = m0 + wr + i*16 + quad*4 + r;
        const int col = n0 + wc + j*16 + ln;
        const float v = acc[i][j][r];
        if (MODE == 1){
          Cf[(size_t)row * 2048 + col] = v;
        } else {
          if (col < 2048)       Cq[(size_t)row * 2048 + col]          = f2b(v);
          else if (col < 2560)  Ck[(size_t)row * 512  + (col - 2048)] = f2b(v);
          else                  Cv[(size_t)(col - 2560) * 2048 + row] = f2b(v);
        }
      }
}

// ------------- fused RoPE in place on q (16 heads) and k (4 heads) ---------
__global__ void rope2_k(u16* __restrict__ q, u16* __restrict__ k){
  const int s = blockIdx.x;
  #pragma unroll
  for (int it = 0; it < 5; ++it){
    const int p = it * 256 + threadIdx.x;          // 1024 q pairs + 256 k pairs
    int hh, i; u16* base;
    if (p < 1024){
      hh = p >> 6; i = p & 63;
      base = q + (size_t)s * 2048 + hh * 128 + i;
    } else {
      const int pp = p - 1024;
      hh = pp >> 6; i = pp & 63;
      base = k + (size_t)s * 512 + hh * 128 + i;
    }
    const float inv = __expf(-(float)i * 0.14391157f);  // 10000^(-i/64)
    const float ang = (float)s * inv;
    float c, sn;
    sincosf(ang, &sn, &c);
    const float x1 = b2f(base[0]), x2 = b2f(base[64]);
    base[0]  = f2b(x1 * c - x2 * sn);
    base[64] = f2b(x2 * c + x1 * sn);
  }
}

// ------------- MFMA diff-attention v7: single-QK, f16 E-in-regs ------------
// (unchanged from R8)
__global__ __launch_bounds__(256) void attn_k(const u16* __restrict__ q,
                                              const u16* __restrict__ kk,
                                              const u16* __restrict__ vt,
                                              const float* __restrict__ lam,
                                              u16* __restrict__ ctx){
  const int h   = blockIdx.x >> 5;
  const int qt  = blockIdx.x & 31;
  const int qt0 = qt << 6;
  const int tid = threadIdx.x;
  const int w = tid >> 6, lane = tid & 63;
  const int quad = lane >> 4, ln = lane & 15;
  const int kvh = h >> 2;
  const float lam_h = lam[h];
  const float scale = 0.125f;   // 1/sqrt(64)
  const int qbw = qt0 + (w << 4);           // this wave's 16 q rows

  __shared__ __align__(16) u16 Ks[2][32 * 128];   // 16 KB
  __shared__ __align__(16) u16 Vs[2][128 * 32];   // 16 KB
  __shared__ __align__(16) u16 p_lds[4][2][16][40];

  s8b qf[4];   // A-layout: m = ln, k-slot (quad, s)
  {
    const u16* qrow = q + (size_t)(qbw + ln) * 2048 + h * 128 + quad * 8;
    #pragma unroll
    for (int s = 0; s < 4; ++s) qf[s] = *(const s8b*)(qrow + s * 32);
  }

  const int tlo = (qt0 > 511) ? ((qt0 - 511) >> 5) : 0;
  const int thi = ((qt0 + 63) >> 5) + 1;    // block-union tiles; thi-tlo <= 18

#define STAGE_K(buf, t) {                                                         \
    const int kc = (t) << 5;                                                      \
    _Pragma("unroll")                                                             \
    for (int i_ = 0; i_ < 2; ++i_){                                               \
      const int slot = tid + i_ * 256;                                            \
      const int row_ = slot >> 4, c16_ = slot & 15;                               \
      const u16* src_ = kk + (size_t)(kc + row_) * 512 + kvh * 128                \
                        + ((c16_ ^ (row_ & 7)) << 3);                             \
      gload16(src_, &Ks[buf][slot * 8]);                                          \
    } }
#define STAGE_V(buf, t) {                                                         \
    const int kc = (t) << 5;                                                      \
    _Pragma("unroll")                                                             \
    for (int i_ = 0; i_ < 2; ++i_){                                               \
      const int slot = tid + i_ * 256;                                            \
      const int row_ = slot >> 2, c16_ = slot & 3;                                \
      const u16* src_ = vt + (size_t)(kvh * 128 + row_) * 2048 + kc               \
                        + ((c16_ ^ ((row_ >> 1) & 3)) << 3);                      \
      gload16(src_, &Vs[buf][slot * 8]);                                          \
    } }

  // ---- Pass A: K staged; QK^T + exp ONCE; E -> f16 regs; l sums ----
  h8 eh[18], eh2[18];    // static-indexed only (full unroll)
  float l1[4] = {0.f,0.f,0.f,0.f}, l2[4] = {0.f,0.f,0.f,0.f};

  STAGE_K(0, tlo);
  asm volatile("s_waitcnt vmcnt(0)" ::: "memory");
  __builtin_amdgcn_s_barrier();
  #pragma unroll
  for (int tt = 0; tt < 18; ++tt){
    const int t = tlo + tt;
    if (t >= thi) continue;                  // block-uniform
    const int cur = tt & 1;
    if (t + 1 < thi){
      STAGE_K(cur ^ 1, t + 1);
      asm volatile("s_waitcnt vmcnt(2)" ::: "memory");
    } else {
      asm volatile("s_waitcnt vmcnt(0)" ::: "memory");
    }
    __builtin_amdgcn_s_barrier();
    const int kcol0 = t << 5;
    if (kcol0 <= qbw + 15 && kcol0 + 31 >= qbw - 511){   // wave-uniform
      #pragma unroll
      for (int sub = 0; sub < 2; ++sub){
        const int krow = (sub*16 + ln) * 128;
        s8b kf0 = *(const s8b*)&Ks[cur][krow + (((quad +  0) ^ (ln & 7)) << 3)];
        s8b kf1 = *(const s8b*)&Ks[cur][krow + (((quad +  4) ^ (ln & 7)) << 3)];
        s8b kf2 = *(const s8b*)&Ks[cur][krow + (((quad +  8) ^ (ln & 7)) << 3)];
        s8b kf3 = *(const s8b*)&Ks[cur][krow + (((quad + 12) ^ (ln & 7)) << 3)];
        f4 z = {0.f,0.f,0.f,0.f};
        f4 s1 = mfma16(qf[1], kf1, mfma16(qf[0], kf0, z));
        f4 s2 = mfma16(qf[3], kf3, mfma16(qf[2], kf2, z));
        const int col = kcol0 + sub*16 + ln;
        h8 ev;
        #pragma unroll
        for (int r = 0; r < 4; ++r){
          const int row = qbw + quad*4 + r;
          const bool ok = (col <= row) && (col > row - 512);
          const float a = ok ? __expf(s1[r] * scale) * 0.0625f : 0.f;
          const float b = ok ? __expf(s2[r] * scale) * 0.0625f : 0.f;
          l1[r] += a; l2[r] += b;
          ev[2*r]   = (_Float16)a;
          ev[2*r+1] = (_Float16)b;
        }
        if (sub == 0) eh[tt] = ev; else eh2[tt] = ev;
      }
    }
    asm volatile("s_waitcnt lgkmcnt(0)" ::: "memory");
    __builtin_amdgcn_s_barrier();
  }
  #pragma unroll
  for (int r = 0; r < 4; ++r){
    #pragma unroll
    for (int off = 1; off < 16; off <<= 1){
      l1[r] += __shfl_xor(l1[r], off, 16);
      l2[r] += __shfl_xor(l2[r], off, 16);
    }
  }
  float il1[4], il2[4];
  #pragma unroll
  for (int r = 0; r < 4; ++r){ il1[r] = 1.f / l1[r]; il2[r] = 1.f / l2[r]; }

  // ---- Pass B: V staged; P from E regs; p_lds; PV ----
  f4 acc[8];
  #pragma unroll
  for (int dt = 0; dt < 8; ++dt){ f4 z = {0.f,0.f,0.f,0.f}; acc[dt] = z; }
  float den[4] = {0.f,0.f,0.f,0.f};

  STAGE_V(0, tlo);
  asm volatile("s_waitcnt vmcnt(0)" ::: "memory");
  __builtin_amdgcn_s_barrier();
  #pragma unroll
  for (int tt = 0; tt < 18; ++tt){
    const int t = tlo + tt;
    if (t >= thi) continue;                  // block-uniform
    const int cur = tt & 1;
    if (t + 1 < thi){
      STAGE_V(cur ^ 1, t + 1);
      asm volatile("s_waitcnt vmcnt(2)" ::: "memory");
    } else {
      asm volatile("s_waitcnt vmcnt(0)" ::: "memory");
    }
    __builtin_amdgcn_s_barrier();
    const int kcol0 = t << 5;
    if (kcol0 <= qbw + 15 && kcol0 + 31 >= qbw - 511){   // wave-uniform
      #pragma unroll
      for (int sub = 0; sub < 2; ++sub){
        const h8 ev = (sub == 0) ? eh[tt] : eh2[tt];
        #pragma unroll
        for (int r = 0; r < 4; ++r){
          const float a = (float)ev[2*r];
          const float b = (float)ev[2*r+1];
          const float pd = fmaxf(a * il1[r] - lam_h * (b * il2[r]), 0.f);
          den[r] += pd;
          p_lds[w][cur][quad*4 + r][sub*16 + ln] = f2b(pd);
        }
      }
      // per-wave LDS slice: within-wave RAW handled by lgkmcnt.
      s8b pf = *(const s8b*)&p_lds[w][cur][ln][quad * 8];
      #pragma unroll
      for (int dt = 0; dt < 8; ++dt){
        s8b vf = *(const s8b*)&Vs[cur][(dt*16 + ln)*32 + (((quad) ^ ((ln >> 1) & 3)) << 3)];
        acc[dt] = mfma16(pf, vf, acc[dt]);
      }
    }
    asm volatile("s_waitcnt lgkmcnt(0)" ::: "memory");
    __builtin_amdgcn_s_barrier();
  }

  #pragma unroll
  for (int r = 0; r < 4; ++r)
    #pragma unroll
    for (int off = 1; off < 16; off <<= 1)
      den[r] += __shfl_xor(den[r], off, 16);
  #pragma unroll
  for (int r = 0; r < 4; ++r){
    const float dn = 1.f / (den[r] + 1e-6f);
    const int row = qbw + quad*4 + r;
    u16* orow = ctx + (size_t)row * 2048 + h * 128 + ln;
    #pragma unroll
    for (int dt = 0; dt < 8; ++dt)
      orow[dt * 16] = f2b(acc[dt][r] * dn);
  }
#undef STAGE_K
#undef STAGE_V
}

// ------------- launch ------------------------------------------------------
extern "C" void kernel_launch(void* const* d_in, const int* in_sizes, int n_in,
                              void* d_out, int out_size, void* d_ws, size_t ws_size,
                              hipStream_t stream){
  (void)in_sizes; (void)n_in; (void)out_size; (void)ws_size;
  const float* x   = (const float*)d_in[0];
  const float* Wq  = (const float*)d_in[1];
  const float* Wk  = (const float*)d_in[2];
  const float* Wv  = (const float*)d_in[3];
  const float* Wo  = (const float*)d_in[4];
  const float* lam = (const float*)d_in[5];
  char* ws = (char*)d_ws;
  // ws (<=17.1 MB of the 20 MB budget):
  //   WT  [0, 12.6)  fused [WqT;WkT;WvT] = 3072x2048 bf16
  //   kb  [13, 15)   roped k
  //   vtb [15, 17)   v^T
  //   ctx [0, 8)     reuse of WT after fused gemm
  //   WoT [8, 16)    reuse after attn (kb/vtb dead)
  u16* WT  = (u16*)(ws);
  u16* kb  = (u16*)(ws + (size_t)(13u << 20));
  u16* vtb = (u16*)(ws + (size_t)(15u << 20));
  u16* ctx = WT;
  u16* WoT = (u16*)(ws + (size_t)( 8u << 20));
  // d_out (16 MB fp32): xb [0,8), qb [8,16). Both dead before the final gemm,
  // which reads only ctx/WoT (ws) and overwrites all of d_out.
  u16* xb  = (u16*)d_out;
  u16* qb  = (u16*)((char*)d_out + (size_t)(8u << 20));
  float* out = (float*)d_out;

  const dim3 tb(32, 8);
  convert_k<<<2048, 256, 0, stream>>>(x, xb, 2048 * 2048 / 8);
  // fused weight transpose: WT rows [0,2048)=WqT, [2048,2560)=WkT, [2560,3072)=WvT
  transpose3_k<<<dim3(96, 64), tb, 0, stream>>>(Wq, Wk, Wv, WT);
  // fused QKV projection: [q | k | v^T]
  gemm8<0><<<dim3(24, 16), 256, 0, stream>>>(xb, WT, qb, kb, vtb, nullptr, 2048, 2048);
  // fused RoPE (q and k)
  rope2_k<<<2048, 256, 0, stream>>>(qb, kb);
  // diff-attention -> ctx (64 q-rows/block, single-QK + E-in-regs)
  attn_k<<<512, 256, 0, stream>>>(qb, kb, vtb, lam, ctx);
  // out = ctx @ Wo
  transpose_k<<<dim3(64, 64), tb, 0, stream>>>(Wo, WoT, 2048, 2048);
  gemm8<1><<<dim3(16, 16), 256, 0, stream>>>(ctx, WoT, nullptr, nullptr, nullptr, out, 2048, 2048);
}

// Round 13
// 222.325 us; speedup vs baseline: 1.1962x; 1.1962x over previous
//
#include <hip/hip_runtime.h>

typedef unsigned short u16;
typedef __attribute__((ext_vector_type(8))) short s8b;       // 8 x bf16 bits
typedef __attribute__((ext_vector_type(4))) float f4;
typedef __attribute__((ext_vector_type(8))) _Float16 h8;     // 8 x f16

static __device__ __forceinline__ float b2f(u16 u){
  return __uint_as_float(((unsigned int)u) << 16);
}
static __device__ __forceinline__ u16 f2b(float f){
  unsigned int u = __float_as_uint(f);
  u = (u + 0x7FFFu + ((u >> 16) & 1u)) >> 16;   // RNE
  return (u16)u;
}
static __device__ __forceinline__ f4 mfma16(s8b a, s8b b, f4 c){
  return __builtin_amdgcn_mfma_f32_16x16x32_bf16(a, b, c, 0, 0, 0);
}
static __device__ __forceinline__ s8b load8(const float* p){
  float4 a = ((const float4*)p)[0];
  float4 b = ((const float4*)p)[1];
  s8b r;
  r[0] = (short)f2b(a.x); r[1] = (short)f2b(a.y);
  r[2] = (short)f2b(a.z); r[3] = (short)f2b(a.w);
  r[4] = (short)f2b(b.x); r[5] = (short)f2b(b.y);
  r[6] = (short)f2b(b.z); r[7] = (short)f2b(b.w);
  return r;
}
// async global->LDS, 16B per lane. Per-lane lds ptr must equal wave-uniform + lane*16.
static __device__ __forceinline__ void gload16(const u16* g, u16* l){
  __builtin_amdgcn_global_load_lds((const __attribute__((address_space(1))) void*)g,
                                   (__attribute__((address_space(3))) void*)l,
                                   16, 0, 0);
}

// ------------- fused prep: x->bf16 convert + Wq/Wk/Wv transpose ------------
// blocks [0,2048): convert (256 thr x 8 elems = exactly 2048^2 fp32).
// blocks [2048,8192): transpose3 (6144 = 96 x-tiles x 64 k-tiles).
__global__ void prep_k(const float* __restrict__ x, u16* __restrict__ xb,
                       const float* __restrict__ Wq, const float* __restrict__ Wk,
                       const float* __restrict__ Wv, u16* __restrict__ WT){
  __shared__ u16 tile[32][33];
  const int bx = blockIdx.x;
  if (bx < 2048){
    const int i = bx * 256 + threadIdx.x;
    ((s8b*)xb)[i] = load8(x + (size_t)i * 8);
    return;
  }
  const int b2 = bx - 2048;
  int nb = b2 % 96;
  const int kb_ = b2 / 96;
  const float* src; int N; int rowoff;
  if (nb < 64)      { src = Wq; N = 2048; rowoff = 0; }
  else if (nb < 80) { src = Wk; N = 512;  rowoff = 2048; nb -= 64; }
  else              { src = Wv; N = 512;  rowoff = 2560; nb -= 80; }
  const int n0 = nb << 5, k0 = kb_ << 5;
  const int tx = threadIdx.x & 31, ty = threadIdx.x >> 5;
  #pragma unroll
  for (int i = ty; i < 32; i += 8)
    tile[i][tx] = f2b(src[(size_t)(k0 + i) * N + n0 + tx]);
  __syncthreads();
  #pragma unroll
  for (int i = ty; i < 32; i += 8)
    WT[(size_t)(rowoff + n0 + i) * 2048 + k0 + tx] = tile[tx][i];
}

// ------------- transpose: in[K][N] fp32 -> out[N][K] bf16 (Wo only) --------
__global__ void transpose_k(const float* __restrict__ in, u16* __restrict__ out,
                            int K, int N){
  __shared__ u16 tile[32][33];
  const int n0 = blockIdx.x << 5, k0 = blockIdx.y << 5;
  const int tx = threadIdx.x, ty = threadIdx.y;   // block (32,8)
  #pragma unroll
  for (int i = ty; i < 32; i += 8)
    tile[i][tx] = f2b(in[(size_t)(k0 + i) * N + n0 + tx]);
  __syncthreads();
  #pragma unroll
  for (int i = ty; i < 32; i += 8)
    out[(size_t)(n0 + i) * K + k0 + tx] = tile[tx][i];
}

// ------------- 8-wave MFMA GEMM, 128x128 tile, BK=32, 2-phase dbuf ---------
// R13: R8-exact loop (proven 53us best: 8 waves, vmcnt(2), zero-conflict XOR
// swizzle, no T1). Last-iter reload guarded (no stale async loads). MODE 0:
// RoPE fused into the epilogue for q/k tiles — each 128-wide n-tile is purely
// one head region (boundaries 128-aligned): acc->bf16 into padded LDS tile
// (reuses dead staging LDS), barrier, read (x_c, x_c^64), rotate, store.
// Bit-identical to the old separate rope pass (same round->rope->round).
template <int MODE>
__global__ __launch_bounds__(512) void gemm8(const u16* __restrict__ A,
                                             const u16* __restrict__ Bt,
                                             u16* __restrict__ Cq,
                                             u16* __restrict__ Ck,
                                             u16* __restrict__ Cv,
                                             float* __restrict__ Cf,
                                             int M, int K){
  // staging: A at [cur*4096), B at [8192 + cur*4096); rope tile aliases all.
  __shared__ __align__(16) u16 smem[(MODE == 0) ? 17408 : 16384];
  const int n0 = blockIdx.x << 7;
  const int m0 = blockIdx.y << 7;
  const int tid = threadIdx.x;
  const int wave = tid >> 6, lane = tid & 63;
  const int quad = lane >> 4, ln = lane & 15;
  const int wr = (wave >> 2) << 6;     // 0 / 64
  const int wc = (wave & 3) << 5;      // 0 / 32 / 64 / 96
  const int lr = tid >> 2;                        // staged row
  const int lc = (((tid & 3) ^ ((tid >> 3) & 3)) << 3);  // pre-swizzled src granule

  f4 acc[4][2];
  #pragma unroll
  for (int i = 0; i < 4; ++i)
    #pragma unroll
    for (int j = 0; j < 2; ++j){ f4 z = {0.f,0.f,0.f,0.f}; acc[i][j] = z; }

  const u16* ag = A  + (size_t)(m0 + lr) * K + lc;
  const u16* bg = Bt + (size_t)(n0 + lr) * K + lc;
  const int NT = K >> 5;
  const int rsw = ((ln >> 1) & 3) << 3;           // read-side XOR partner

  gload16(ag, smem + tid * 8);
  gload16(bg, smem + 8192 + tid * 8);

  for (int t = 0; t < NT; ++t){
    const int cur = t & 1;
    if (t + 1 < NT){
      const int kn = (t + 1) << 5;
      gload16(ag + kn, smem + (cur ^ 1) * 4096 + tid * 8);
      gload16(bg + kn, smem + 8192 + (cur ^ 1) * 4096 + tid * 8);
      asm volatile("s_waitcnt vmcnt(2)" ::: "memory");
    } else {
      asm volatile("s_waitcnt vmcnt(0)" ::: "memory");
    }
    __builtin_amdgcn_s_barrier();
    s8b af[4], bf[2];
    #pragma unroll
    for (int i = 0; i < 4; ++i)
      af[i] = *(const s8b*)&smem[cur*4096 + (wr + i*16 + ln)*32 + ((quad*8) ^ rsw)];
    #pragma unroll
    for (int j = 0; j < 2; ++j)
      bf[j] = *(const s8b*)&smem[8192 + cur*4096 + (wc + j*16 + ln)*32 + ((quad*8) ^ rsw)];
    #pragma unroll
    for (int i = 0; i < 4; ++i)
      #pragma unroll
      for (int j = 0; j < 2; ++j)
        acc[i][j] = mfma16(af[i], bf[j], acc[i][j]);
    asm volatile("s_waitcnt lgkmcnt(0)" ::: "memory");
    __builtin_amdgcn_s_barrier();
  }

  // C/D layout: col = ln, row = quad*4 + r (m89/m91-verified)
  if (MODE == 1){
    #pragma unroll
    for (int i = 0; i < 4; ++i)
      #pragma unroll
      for (int j = 0; j < 2; ++j)
        #pragma unroll
        for (int r = 0; r < 4; ++r){
          const int row = m0 + wr + i*16 + quad*4 + r;
          const int col = n0 + wc + j*16 + ln;
          Cf[(size_t)row * 2048 + col] = acc[i][j][r];
        }
  } else if (n0 >= 2560){
    // v tile: store transposed, no rope
    #pragma unroll
    for (int i = 0; i < 4; ++i)
      #pragma unroll
      for (int j = 0; j < 2; ++j)
        #pragma unroll
        for (int r = 0; r < 4; ++r){
          const int row = m0 + wr + i*16 + quad*4 + r;
          const int col = n0 + wc + j*16 + ln;
          Cv[(size_t)(col - 2560) * 2048 + row] = f2b(acc[i][j][r]);
        }
  } else {
    // q or k tile: rope in epilogue. All staging loads retired (last-iter
    // guard) and all waves passed the final barrier -> safe to reuse smem.
    #pragma unroll
    for (int i = 0; i < 4; ++i)
      #pragma unroll
      for (int j = 0; j < 2; ++j)
        #pragma unroll
        for (int r = 0; r < 4; ++r)
          smem[(wr + i*16 + quad*4 + r) * 136 + wc + j*16 + ln] = f2b(acc[i][j][r]);
    asm volatile("s_waitcnt lgkmcnt(0)" ::: "memory");
    __builtin_amdgcn_s_barrier();
    #pragma unroll
    for (int j = 0; j < 2; ++j){
      const int c  = wc + j*16 + ln;       // i within head == local col (128-aligned tiles)
      const int iq = c & 63;
      const float inv = __expf(-(float)iq * 0.14391157f);  // 10000^(-iq/64)
      #pragma unroll
      for (int i = 0; i < 4; ++i)
        #pragma unroll
        for (int r = 0; r < 4; ++r){
          const int rl  = wr + i*16 + quad*4 + r;
          const int row = m0 + rl;
          float cs, sn;
          sincosf((float)row * inv, &sn, &cs);
          const float xv = b2f(smem[rl*136 + c]);
          const float xp = b2f(smem[rl*136 + (c ^ 64)]);
          const float res = (c < 64) ? (xv*cs - xp*sn) : (xv*cs + xp*sn);
          if (n0 < 2048) Cq[(size_t)row * 2048 + n0 + c]          = f2b(res);
          else           Ck[(size_t)row * 512  + (n0 - 2048) + c] = f2b(res);
        }
    }
  }
}

// ------------- MFMA diff-attention v7: single-QK, f16 E-in-regs ------------
// (unchanged from R8)
__global__ __launch_bounds__(256) void attn_k(const u16* __restrict__ q,
                                              const u16* __restrict__ kk,
                                              const u16* __restrict__ vt,
                                              const float* __restrict__ lam,
                                              u16* __restrict__ ctx){
  const int h   = blockIdx.x >> 5;
  const int qt  = blockIdx.x & 31;
  const int qt0 = qt << 6;
  const int tid = threadIdx.x;
  const int w = tid >> 6, lane = tid & 63;
  const int quad = lane >> 4, ln = lane & 15;
  const int kvh = h >> 2;
  const float lam_h = lam[h];
  const float scale = 0.125f;   // 1/sqrt(64)
  const int qbw = qt0 + (w << 4);           // this wave's 16 q rows

  __shared__ __align__(16) u16 Ks[2][32 * 128];   // 16 KB
  __shared__ __align__(16) u16 Vs[2][128 * 32];   // 16 KB
  __shared__ __align__(16) u16 p_lds[4][2][16][40];

  s8b qf[4];   // A-layout: m = ln, k-slot (quad, s)
  {
    const u16* qrow = q + (size_t)(qbw + ln) * 2048 + h * 128 + quad * 8;
    #pragma unroll
    for (int s = 0; s < 4; ++s) qf[s] = *(const s8b*)(qrow + s * 32);
  }

  const int tlo = (qt0 > 511) ? ((qt0 - 511) >> 5) : 0;
  const int thi = ((qt0 + 63) >> 5) + 1;    // block-union tiles; thi-tlo <= 18

#define STAGE_K(buf, t) {                                                         \
    const int kc = (t) << 5;                                                      \
    _Pragma("unroll")                                                             \
    for (int i_ = 0; i_ < 2; ++i_){                                               \
      const int slot = tid + i_ * 256;                                            \
      const int row_ = slot >> 4, c16_ = slot & 15;                               \
      const u16* src_ = kk + (size_t)(kc + row_) * 512 + kvh * 128                \
                        + ((c16_ ^ (row_ & 7)) << 3);                             \
      gload16(src_, &Ks[buf][slot * 8]);                                          \
    } }
#define STAGE_V(buf, t) {                                                         \
    const int kc = (t) << 5;                                                      \
    _Pragma("unroll")                                                             \
    for (int i_ = 0; i_ < 2; ++i_){                                               \
      const int slot = tid + i_ * 256;                                            \
      const int row_ = slot >> 2, c16_ = slot & 3;                                \
      const u16* src_ = vt + (size_t)(kvh * 128 + row_) * 2048 + kc               \
                        + ((c16_ ^ ((row_ >> 1) & 3)) << 3);                      \
      gload16(src_, &Vs[buf][slot * 8]);                                          \
    } }

  // ---- Pass A: K staged; QK^T + exp ONCE; E -> f16 regs; l sums ----
  h8 eh[18], eh2[18];    // static-indexed only (full unroll)
  float l1[4] = {0.f,0.f,0.f,0.f}, l2[4] = {0.f,0.f,0.f,0.f};

  STAGE_K(0, tlo);
  asm volatile("s_waitcnt vmcnt(0)" ::: "memory");
  __builtin_amdgcn_s_barrier();
  #pragma unroll
  for (int tt = 0; tt < 18; ++tt){
    const int t = tlo + tt;
    if (t >= thi) continue;                  // block-uniform
    const int cur = tt & 1;
    if (t + 1 < thi){
      STAGE_K(cur ^ 1, t + 1);
      asm volatile("s_waitcnt vmcnt(2)" ::: "memory");
    } else {
      asm volatile("s_waitcnt vmcnt(0)" ::: "memory");
    }
    __builtin_amdgcn_s_barrier();
    const int kcol0 = t << 5;
    if (kcol0 <= qbw + 15 && kcol0 + 31 >= qbw - 511){   // wave-uniform
      #pragma unroll
      for (int sub = 0; sub < 2; ++sub){
        const int krow = (sub*16 + ln) * 128;
        s8b kf0 = *(const s8b*)&Ks[cur][krow + (((quad +  0) ^ (ln & 7)) << 3)];
        s8b kf1 = *(const s8b*)&Ks[cur][krow + (((quad +  4) ^ (ln & 7)) << 3)];
        s8b kf2 = *(const s8b*)&Ks[cur][krow + (((quad +  8) ^ (ln & 7)) << 3)];
        s8b kf3 = *(const s8b*)&Ks[cur][krow + (((quad + 12) ^ (ln & 7)) << 3)];
        f4 z = {0.f,0.f,0.f,0.f};
        f4 s1 = mfma16(qf[1], kf1, mfma16(qf[0], kf0, z));
        f4 s2 = mfma16(qf[3], kf3, mfma16(qf[2], kf2, z));
        const int col = kcol0 + sub*16 + ln;
        h8 ev;
        #pragma unroll
        for (int r = 0; r < 4; ++r){
          const int row = qbw + quad*4 + r;
          const bool ok = (col <= row) && (col > row - 512);
          const float a = ok ? __expf(s1[r] * scale) * 0.0625f : 0.f;
          const float b = ok ? __expf(s2[r] * scale) * 0.0625f : 0.f;
          l1[r] += a; l2[r] += b;
          ev[2*r]   = (_Float16)a;
          ev[2*r+1] = (_Float16)b;
        }
        if (sub == 0) eh[tt] = ev; else eh2[tt] = ev;
      }
    }
    asm volatile("s_waitcnt lgkmcnt(0)" ::: "memory");
    __builtin_amdgcn_s_barrier();
  }
  #pragma unroll
  for (int r = 0; r < 4; ++r){
    #pragma unroll
    for (int off = 1; off < 16; off <<= 1){
      l1[r] += __shfl_xor(l1[r], off, 16);
      l2[r] += __shfl_xor(l2[r], off, 16);
    }
  }
  float il1[4], il2[4];
  #pragma unroll
  for (int r = 0; r < 4; ++r){ il1[r] = 1.f / l1[r]; il2[r] = 1.f / l2[r]; }

  // ---- Pass B: V staged; P from E regs; p_lds; PV ----
  f4 acc[8];
  #pragma unroll
  for (int dt = 0; dt < 8; ++dt){ f4 z = {0.f,0.f,0.f,0.f}; acc[dt] = z; }
  float den[4] = {0.f,0.f,0.f,0.f};

  STAGE_V(0, tlo);
  asm volatile("s_waitcnt vmcnt(0)" ::: "memory");
  __builtin_amdgcn_s_barrier();
  #pragma unroll
  for (int tt = 0; tt < 18; ++tt){
    const int t = tlo + tt;
    if (t >= thi) continue;                  // block-uniform
    const int cur = tt & 1;
    if (t + 1 < thi){
      STAGE_V(cur ^ 1, t + 1);
      asm volatile("s_waitcnt vmcnt(2)" ::: "memory");
    } else {
      asm volatile("s_waitcnt vmcnt(0)" ::: "memory");
    }
    __builtin_amdgcn_s_barrier();
    const int kcol0 = t << 5;
    if (kcol0 <= qbw + 15 && kcol0 + 31 >= qbw - 511){   // wave-uniform
      #pragma unroll
      for (int sub = 0; sub < 2; ++sub){
        const h8 ev = (sub == 0) ? eh[tt] : eh2[tt];
        #pragma unroll
        for (int r = 0; r < 4; ++r){
          const float a = (float)ev[2*r];
          const float b = (float)ev[2*r+1];
          const float pd = fmaxf(a * il1[r] - lam_h * (b * il2[r]), 0.f);
          den[r] += pd;
          p_lds[w][cur][quad*4 + r][sub*16 + ln] = f2b(pd);
        }
      }
      // per-wave LDS slice: within-wave RAW handled by lgkmcnt.
      s8b pf = *(const s8b*)&p_lds[w][cur][ln][quad * 8];
      #pragma unroll
      for (int dt = 0; dt < 8; ++dt){
        s8b vf = *(const s8b*)&Vs[cur][(dt*16 + ln)*32 + (((quad) ^ ((ln >> 1) & 3)) << 3)];
        acc[dt] = mfma16(pf, vf, acc[dt]);
      }
    }
    asm volatile("s_waitcnt lgkmcnt(0)" ::: "memory");
    __builtin_amdgcn_s_barrier();
  }

  #pragma unroll
  for (int r = 0; r < 4; ++r)
    #pragma unroll
    for (int off = 1; off < 16; off <<= 1)
      den[r] += __shfl_xor(den[r], off, 16);
  #pragma unroll
  for (int r = 0; r < 4; ++r){
    const float dn = 1.f / (den[r] + 1e-6f);
    const int row = qbw + quad*4 + r;
    u16* orow = ctx + (size_t)row * 2048 + h * 128 + ln;
    #pragma unroll
    for (int dt = 0; dt < 8; ++dt)
      orow[dt * 16] = f2b(acc[dt][r] * dn);
  }
#undef STAGE_K
#undef STAGE_V
}

// ------------- launch ------------------------------------------------------
extern "C" void kernel_launch(void* const* d_in, const int* in_sizes, int n_in,
                              void* d_out, int out_size, void* d_ws, size_t ws_size,
                              hipStream_t stream){
  (void)in_sizes; (void)n_in; (void)out_size; (void)ws_size;
  const float* x   = (const float*)d_in[0];
  const float* Wq  = (const float*)d_in[1];
  const float* Wk  = (const float*)d_in[2];
  const float* Wv  = (const float*)d_in[3];
  const float* Wo  = (const float*)d_in[4];
  const float* lam = (const float*)d_in[5];
  char* ws = (char*)d_ws;
  // ws (<=17.1 MB of the 20 MB budget):
  //   WT  [0, 12.6)  fused [WqT;WkT;WvT] = 3072x2048 bf16
  //   kb  [13, 15)   roped k
  //   vtb [15, 17)   v^T
  //   ctx [0, 8)     reuse of WT after fused gemm
  //   WoT [8, 16)    reuse after attn (kb/vtb dead)
  u16* WT  = (u16*)(ws);
  u16* kb  = (u16*)(ws + (size_t)(13u << 20));
  u16* vtb = (u16*)(ws + (size_t)(15u << 20));
  u16* ctx = WT;
  u16* WoT = (u16*)(ws + (size_t)( 8u << 20));
  // d_out (16 MB fp32): xb [0,8), qb [8,16). Both dead before the final gemm,
  // which reads only ctx/WoT (ws) and overwrites all of d_out.
  u16* xb  = (u16*)d_out;
  u16* qb  = (u16*)((char*)d_out + (size_t)(8u << 20));
  float* out = (float*)d_out;

  const dim3 tb(32, 8);
  // fused prep: x->bf16 + weight transposes (one launch)
  prep_k<<<8192, 256, 0, stream>>>(x, xb, Wq, Wk, Wv, WT);
  // fused QKV projection with in-epilogue RoPE: [q | k | v^T], q/k pre-roped
  gemm8<0><<<dim3(24, 16), 512, 0, stream>>>(xb, WT, qb, kb, vtb, nullptr, 2048, 2048);
  // diff-attention -> ctx (64 q-rows/block, single-QK + E-in-regs)
  attn_k<<<512, 256, 0, stream>>>(qb, kb, vtb, lam, ctx);
  // out = ctx @ Wo
  transpose_k<<<dim3(64, 64), tb, 0, stream>>>(Wo, WoT, 2048, 2048);
  gemm8<1><<<dim3(16, 16), 512, 0, stream>>>(ctx, WoT, nullptr, nullptr, nullptr, out, 2048, 2048);
}